// Round 5
// baseline (588.240 us; speedup 1.0000x reference)
//
#include <hip/hip_runtime.h>

#define F1 64
#define F2 32
#define FIN 13
#define BSH 9                 // bucket = dst >> 9  (512 nodes/bucket)
#define BNODES 512
#define TILE 16384            // edges per scatter block

// ---------- in-degree histogram ----------
__global__ void k_degree(const int* __restrict__ dst, int* __restrict__ indeg, int E) {
    int e = blockIdx.x * blockDim.x + threadIdx.x;
    if (e < E) atomicAdd(&indeg[dst[e]], 1);
}

// ---------- dinv = rsqrt(deg+1) ----------
__global__ void k_dinv(const int* __restrict__ indeg, float* __restrict__ dinv, int N) {
    int i = blockIdx.x * blockDim.x + threadIdx.x;
    if (i < N) dinv[i] = rsqrtf((float)(indeg[i] + 1));
}

// ---------- bucket histogram (LDS-staged) ----------
__global__ void k_bhist(const int* __restrict__ dst, int* __restrict__ bhist,
                        int E, int NBK) {
    __shared__ int lh[256];
    int tid = threadIdx.x;
    for (int i = tid; i < NBK; i += 256) lh[i] = 0;
    __syncthreads();
    int stride = gridDim.x * 256;
    for (int e = blockIdx.x * 256 + tid; e < E; e += stride)
        atomicAdd(&lh[dst[e] >> BSH], 1);
    __syncthreads();
    for (int i = tid; i < NBK; i += 256)
        if (lh[i]) atomicAdd(&bhist[i], lh[i]);
}

// ---------- scan buckets -> bbase (exclusive), init gcursor ----------
__global__ void k_bscan(const int* __restrict__ bhist, int* __restrict__ bbase,
                        int* __restrict__ gcur, int NBK) {
    __shared__ int s[256];
    int t = threadIdx.x;
    int v = (t < NBK) ? bhist[t] : 0;
    s[t] = v;
    __syncthreads();
    for (int off = 1; off < 256; off <<= 1) {
        int a = (t >= off) ? s[t - off] : 0;
        __syncthreads();
        s[t] += a;
        __syncthreads();
    }
    if (t < NBK) {
        int excl = s[t] - v;
        bbase[t] = excl;
        gcur[t] = excl;
        if (t == NBK - 1) bbase[NBK] = s[t];
    }
}

// ---------- partition edges into bucket-contiguous (dst,src) pairs ----------
__global__ void k_bscatter(const int* __restrict__ src, const int* __restrict__ dst,
                           int* __restrict__ gcur, uint2* __restrict__ pairs,
                           int E, int NBK) {
    __shared__ int lh[256];
    __shared__ int lbase[256];
    int tid = threadIdx.x;
    long t0 = (long)blockIdx.x * TILE;
    int lim = (int)min((long)TILE, (long)E - t0);
    for (int i = tid; i < NBK; i += 256) lh[i] = 0;
    __syncthreads();
    for (int i = tid; i < lim; i += 256)
        atomicAdd(&lh[dst[t0 + i] >> BSH], 1);
    __syncthreads();
    for (int b = tid; b < NBK; b += 256) {
        int c = lh[b];
        lbase[b] = c ? atomicAdd(&gcur[b], c) : 0;
    }
    __syncthreads();
    for (int i = tid; i < NBK; i += 256) lh[i] = 0;
    __syncthreads();
    for (int i = tid; i < lim; i += 256) {
        int d = dst[t0 + i];
        int b = d >> BSH;
        int r = atomicAdd(&lh[b], 1);
        pairs[lbase[b] + r] = make_uint2((unsigned)d, (unsigned)src[t0 + i]);
    }
}

// ---------- xn[v][0..15] = x[v][c]*dinv[v] (c<13), 0 pad ----------
__global__ void k_xn(const float* __restrict__ x, const float* __restrict__ dinv,
                     float* __restrict__ xn, int N) {
    int i = blockIdx.x * blockDim.x + threadIdx.x;
    if (i >= N * 16) return;
    int v = i >> 4, c = i & 15;
    xn[i] = (c < FIN) ? x[(size_t)v * FIN + c] * dinv[v] : 0.f;
}

// ---------- layer1 bucket aggregation: agg1[v] = (xn[v] + sum xn[src]) * dinv[v] ----------
// one block per bucket; LDS acc stride 17 (bank spread); 4 lanes/edge
__global__ void __launch_bounds__(1024)
k_agg1B(const uint2* __restrict__ pairs, const int* __restrict__ bbase,
        const float4* __restrict__ xn, const float* __restrict__ dinv,
        float4* __restrict__ agg1, int N) {
    __shared__ float acc[BNODES * 17];
    int tid = threadIdx.x;
    int bk = blockIdx.x;
    int nodeBase = bk << BSH;
    for (int i = tid; i < BNODES * 17; i += 1024) acc[i] = 0.f;
    __syncthreads();
    int st = bbase[bk], en = bbase[bk + 1];
    int lane = tid & 3;
    for (int e = st + (tid >> 2); e < en; e += 256) {
        uint2 p = pairs[e];
        float4 u = xn[(size_t)p.y * 4 + lane];
        int o = ((int)p.x - nodeBase) * 17 + lane * 4;
        atomicAdd(&acc[o + 0], u.x);
        atomicAdd(&acc[o + 1], u.y);
        atomicAdd(&acc[o + 2], u.z);
        atomicAdd(&acc[o + 3], u.w);
    }
    __syncthreads();
    for (int n = tid >> 2; n < BNODES; n += 256) {
        int v = nodeBase + n;
        if (v >= N) break;
        float4 s = xn[(size_t)v * 4 + lane];   // self
        float dv = dinv[v];
        int o = n * 17 + lane * 4;
        float4 r;
        r.x = (s.x + acc[o + 0]) * dv;
        r.y = (s.y + acc[o + 1]) * dv;
        r.z = (s.z + acc[o + 2]) * dv;
        r.w = (s.w + acc[o + 3]) * dv;
        agg1[(size_t)v * 4 + lane] = r;
    }
}

// ---------- layer1 transform: y2 = (relu(agg1@W1+b1) @ W2) * dinv ----------
// 256 thr, 64 nodes/block
__global__ void k_trans1(const float4* __restrict__ agg1, const float* __restrict__ W1,
                         const float* __restrict__ b1, const float* __restrict__ W2,
                         const float* __restrict__ dinv, float* __restrict__ y2, int N) {
    __shared__ float sW1[FIN * F1];
    __shared__ float sb1[F1];
    __shared__ float sW2[F1 * F2];
    __shared__ float sagg[64][17];
    __shared__ float sh[64][F1];
    int tid = threadIdx.x;
    for (int i = tid; i < FIN * F1; i += 256) sW1[i] = W1[i];
    for (int i = tid; i < F1 * F2; i += 256) sW2[i] = W2[i];
    if (tid < F1) sb1[tid] = b1[tid];
    int ln = tid >> 2;
    int l = tid & 3;
    int base = blockIdx.x * 64;
    int v = base + ln;
    if (v < N) {
        float4 u = agg1[(size_t)v * 4 + l];
        sagg[ln][l * 4 + 0] = u.x;
        sagg[ln][l * 4 + 1] = u.y;
        sagg[ln][l * 4 + 2] = u.z;
        sagg[ln][l * 4 + 3] = u.w;
    }
    __syncthreads();
    {
        int col = tid & 63;
        int sub = tid >> 6;
        for (int nn = sub; nn < 64; nn += 4) {
            if (base + nn >= N) break;
            float acc = sb1[col];
#pragma unroll
            for (int k = 0; k < FIN; ++k) acc += sagg[nn][k] * sW1[k * F1 + col];
            sh[nn][col] = fmaxf(acc, 0.f);
        }
    }
    __syncthreads();
    {
        int ng = tid >> 5;
        int c = tid & 31;
        for (int nn = ng; nn < 64; nn += 8) {
            int v2 = base + nn;
            if (v2 >= N) break;
            float acc = 0.f;
#pragma unroll
            for (int k = 0; k < F1; ++k) acc += sh[nn][k] * sW2[k * F2 + c];
            y2[(size_t)v2 * F2 + c] = acc * dinv[v2];
        }
    }
}

// ---------- layer2 bucket aggregation: out2 = dinv*(y2[v]+sum y2[src]) + b2 ----------
// one block per bucket; LDS acc stride 33; 8 lanes/edge
__global__ void __launch_bounds__(1024)
k_agg2B(const uint2* __restrict__ pairs, const int* __restrict__ bbase,
        const float4* __restrict__ y2, const float* __restrict__ dinv,
        const float* __restrict__ b2, float4* __restrict__ out2, int N) {
    __shared__ float acc[BNODES * 33];
    int tid = threadIdx.x;
    int bk = blockIdx.x;
    int nodeBase = bk << BSH;
    for (int i = tid; i < BNODES * 33; i += 1024) acc[i] = 0.f;
    __syncthreads();
    int st = bbase[bk], en = bbase[bk + 1];
    int lane = tid & 7;
    for (int e = st + (tid >> 3); e < en; e += 128) {
        uint2 p = pairs[e];
        float4 u = y2[(size_t)p.y * 8 + lane];
        int o = ((int)p.x - nodeBase) * 33 + lane * 4;
        atomicAdd(&acc[o + 0], u.x);
        atomicAdd(&acc[o + 1], u.y);
        atomicAdd(&acc[o + 2], u.z);
        atomicAdd(&acc[o + 3], u.w);
    }
    __syncthreads();
    float4 bb = ((const float4*)b2)[lane];
    for (int n = tid >> 3; n < BNODES; n += 128) {
        int v = nodeBase + n;
        if (v >= N) break;
        float4 s = y2[(size_t)v * 8 + lane];
        float dv = dinv[v];
        int o = n * 33 + lane * 4;
        float4 r;
        r.x = (s.x + acc[o + 0]) * dv + bb.x;
        r.y = (s.y + acc[o + 1]) * dv + bb.y;
        r.z = (s.z + acc[o + 2]) * dv + bb.z;
        r.w = (s.w + acc[o + 3]) * dv + bb.w;
        out2[(size_t)v * 8 + lane] = r;
    }
}

// ---------- graph boundaries ----------
__global__ void k_gstart(const int* __restrict__ batch, int* __restrict__ gstart,
                         int N, int G) {
    int g = blockIdx.x * blockDim.x + threadIdx.x;
    if (g > G) return;
    int lo = 0, hi = N;
    while (lo < hi) {
        int mid = (lo + hi) >> 1;
        if (batch[mid] < g) lo = mid + 1; else hi = mid;
    }
    gstart[g] = lo;
}

// ---------- fused mean-pool + MLP ----------
__global__ void k_poolmlp(const float* __restrict__ out2, const int* __restrict__ gstart,
                          const float* __restrict__ fc1w, const float* __restrict__ fc1b,
                          const float* __restrict__ fc2w, const float* __restrict__ fc2b,
                          float* __restrict__ out, int G) {
    __shared__ float sW1[F2 * F2];
    __shared__ float sW2[F2 * F2];
    __shared__ float part[8][F2];
    __shared__ float gvec[F2];
    __shared__ float h1[F2];
    int tid = threadIdx.x;
    for (int i = tid; i < F2 * F2; i += 256) {
        sW1[i] = fc1w[i];
        sW2[i] = fc2w[i];
    }
    int g = blockIdx.x;
    int st = gstart[g], en = gstart[g + 1];
    int r = tid >> 5, c = tid & 31;
    float acc = 0.f;
    for (int v = st + r; v < en; v += 8) acc += out2[(size_t)v * F2 + c];
    part[r][c] = acc;
    __syncthreads();
    if (tid < F2) {
        float s = 0.f;
#pragma unroll
        for (int i = 0; i < 8; ++i) s += part[i][tid];
        float cnt = (float)(en - st);
        gvec[tid] = s / fmaxf(cnt, 1.0f);
    }
    __syncthreads();
    if (tid < F2) {
        float a = fc1b[tid];
#pragma unroll
        for (int k = 0; k < F2; ++k) a += gvec[k] * sW1[k * F2 + tid];
        h1[tid] = fmaxf(a, 0.f);
    }
    __syncthreads();
    if (tid < F2) {
        float a = fc2b[tid];
#pragma unroll
        for (int k = 0; k < F2; ++k) a += h1[k] * sW2[k * F2 + tid];
        out[(size_t)g * F2 + tid] = a;
    }
}

extern "C" void kernel_launch(void* const* d_in, const int* in_sizes, int n_in,
                              void* d_out, int out_size, void* d_ws, size_t ws_size,
                              hipStream_t stream) {
    const float* x    = (const float*)d_in[0];
    const int*   ei   = (const int*)d_in[1];
    const int*   batch= (const int*)d_in[2];
    const float* W1   = (const float*)d_in[3];
    const float* b1   = (const float*)d_in[4];
    const float* W2   = (const float*)d_in[5];
    const float* b2   = (const float*)d_in[6];
    const float* fc1w = (const float*)d_in[7];
    const float* fc1b = (const float*)d_in[8];
    const float* fc2w = (const float*)d_in[9];
    const float* fc2b = (const float*)d_in[10];
    float* out = (float*)d_out;

    const int N = in_sizes[0] / FIN;       // 100000
    const int E = in_sizes[1] / 2;         // 1250000
    const int G = out_size / F2;           // 512
    const int* src = ei;
    const int* dst = ei + E;
    const int NBK = (N + BNODES - 1) >> BSH;   // 196

    // ---- workspace layout (4-byte units) ----
    int* wsi = (int*)d_ws;
    int* indeg  = wsi;                   // N
    int* bhist  = indeg + N;             // NBK   (memset covers indeg..bhist)
    int* bbase  = bhist + NBK;           // NBK+1
    int* gcur   = bbase + NBK + 1;       // NBK
    int* gstart = gcur + NBK;            // G+1
    size_t ioff = (size_t)N + NBK + (NBK + 1) + NBK + (G + 1);
    ioff = (ioff + 3) & ~(size_t)3;      // 16B align
    uint2* pairs = (uint2*)(wsi + ioff); // E uint2 (2E ints)
    size_t foff = ioff + 2 * (size_t)E;
    float* dinv = (float*)(wsi + foff);              // N
    size_t nal = (size_t)((N + 3) & ~3);
    float* xn   = dinv + nal;                        // N*16
    float* agg1 = xn + (size_t)N * 16;               // N*16
    float* y2   = agg1 + (size_t)N * 16;             // N*32
    float* out2 = y2 + (size_t)N * F2;               // N*32

    const int B = 256;
    hipMemsetAsync(indeg, 0, (size_t)(N + NBK) * sizeof(int), stream);

    hipLaunchKernelGGL(k_degree, dim3((E + B - 1) / B), dim3(B), 0, stream, dst, indeg, E);
    hipLaunchKernelGGL(k_dinv, dim3((N + B - 1) / B), dim3(B), 0, stream, indeg, dinv, N);
    hipLaunchKernelGGL(k_bhist, dim3(256), dim3(B), 0, stream, dst, bhist, E, NBK);
    hipLaunchKernelGGL(k_bscan, dim3(1), dim3(B), 0, stream, bhist, bbase, gcur, NBK);
    hipLaunchKernelGGL(k_bscatter, dim3((E + TILE - 1) / TILE), dim3(B), 0, stream,
                       src, dst, gcur, pairs, E, NBK);
    hipLaunchKernelGGL(k_xn, dim3(((long)N * 16 + B - 1) / B), dim3(B), 0, stream,
                       x, dinv, xn, N);
    hipLaunchKernelGGL(k_agg1B, dim3(NBK), dim3(1024), 0, stream,
                       pairs, bbase, (const float4*)xn, dinv, (float4*)agg1, N);
    hipLaunchKernelGGL(k_trans1, dim3((N + 63) / 64), dim3(B), 0, stream,
                       (const float4*)agg1, W1, b1, W2, dinv, y2, N);
    hipLaunchKernelGGL(k_agg2B, dim3(NBK), dim3(1024), 0, stream,
                       pairs, bbase, (const float4*)y2, dinv, b2, (float4*)out2, N);
    hipLaunchKernelGGL(k_gstart, dim3((G + 1 + B - 1) / B), dim3(B), 0, stream,
                       batch, gstart, N, G);
    hipLaunchKernelGGL(k_poolmlp, dim3(G), dim3(B), 0, stream,
                       out2, gstart, fc1w, fc1b, fc2w, fc2b, out, G);
}

// Round 6
// 191.904 us; speedup vs baseline: 3.0653x; 3.0653x over previous
//
#include <hip/hip_runtime.h>

#define F1 64
#define F2 32
#define FIN 13
#define BSH 9                 // bucket = dst >> 9  (512 nodes/bucket)
#define BNODES 512
#define TILE 16384            // edges per scatter block
#define CAP 14336             // max edges sorted in LDS per bucket (mean 6377, >90 sigma)

// ---------- bucket histogram (LDS-staged) ----------
__global__ void k_bhist(const int* __restrict__ dst, int* __restrict__ bhist,
                        int E, int NBK) {
    __shared__ int lh[256];
    int tid = threadIdx.x;
    for (int i = tid; i < NBK; i += 256) lh[i] = 0;
    __syncthreads();
    int stride = gridDim.x * 256;
    for (int e = blockIdx.x * 256 + tid; e < E; e += stride)
        atomicAdd(&lh[dst[e] >> BSH], 1);
    __syncthreads();
    for (int i = tid; i < NBK; i += 256)
        if (lh[i]) atomicAdd(&bhist[i], lh[i]);
}

// ---------- scan buckets -> bbase (exclusive), init gcursor, sentinel rowstart[N]=E ----------
__global__ void k_bscan(const int* __restrict__ bhist, int* __restrict__ bbase,
                        int* __restrict__ gcur, int* __restrict__ rowstart,
                        int NBK, int N, int E) {
    __shared__ int s[256];
    int t = threadIdx.x;
    int v = (t < NBK) ? bhist[t] : 0;
    s[t] = v;
    __syncthreads();
    for (int off = 1; off < 256; off <<= 1) {
        int a = (t >= off) ? s[t - off] : 0;
        __syncthreads();
        s[t] += a;
        __syncthreads();
    }
    if (t < NBK) {
        int excl = s[t] - v;
        bbase[t] = excl;
        gcur[t] = excl;
        if (t == NBK - 1) bbase[NBK] = s[t];
    }
    if (t == 0) rowstart[N] = E;
}

// ---------- partition edges into bucket-contiguous (dst,src) pairs ----------
__global__ void k_bscatter(const int* __restrict__ src, const int* __restrict__ dst,
                           int* __restrict__ gcur, uint2* __restrict__ pairs,
                           int E, int NBK) {
    __shared__ int lh[256];
    __shared__ int lbase[256];
    int tid = threadIdx.x;
    long t0 = (long)blockIdx.x * TILE;
    int lim = (int)min((long)TILE, (long)E - t0);
    for (int i = tid; i < NBK; i += 256) lh[i] = 0;
    __syncthreads();
    for (int i = tid; i < lim; i += 256)
        atomicAdd(&lh[dst[t0 + i] >> BSH], 1);
    __syncthreads();
    for (int b = tid; b < NBK; b += 256) {
        int c = lh[b];
        lbase[b] = c ? atomicAdd(&gcur[b], c) : 0;
    }
    __syncthreads();
    for (int i = tid; i < NBK; i += 256) lh[i] = 0;
    __syncthreads();
    for (int i = tid; i < lim; i += 256) {
        int d = dst[t0 + i];
        int b = d >> BSH;
        int r = atomicAdd(&lh[b], 1);
        pairs[lbase[b] + r] = make_uint2((unsigned)d, (unsigned)src[t0 + i]);
    }
}

// ---------- per-bucket counting sort -> csr (coalesced), rowstart, dinv ----------
__global__ void __launch_bounds__(1024)
k_bsort(const uint2* __restrict__ pairs, const int* __restrict__ bbase,
        int* __restrict__ rowstart, float* __restrict__ dinv,
        int* __restrict__ csr, int N) {
    __shared__ int cnt[BNODES];
    __shared__ int lex[BNODES];
    __shared__ int lcur[BNODES];
    __shared__ int lsorted[CAP];
    int tid = threadIdx.x;
    int bk = blockIdx.x;
    int nodeBase = bk << BSH;
    int st = bbase[bk], en = bbase[bk + 1];
    int m = en - st;
    for (int i = tid; i < BNODES; i += 1024) { cnt[i] = 0; lcur[i] = 0; }
    __syncthreads();
    for (int i = tid; i < m; i += 1024)
        atomicAdd(&cnt[(int)pairs[st + i].x - nodeBase], 1);
    __syncthreads();
    // inclusive scan of cnt -> lex (Hillis-Steele over 512)
    if (tid < BNODES) lex[tid] = cnt[tid];
    __syncthreads();
    for (int off = 1; off < BNODES; off <<= 1) {
        int a = 0;
        if (tid < BNODES && tid >= off) a = lex[tid - off];
        __syncthreads();
        if (tid < BNODES) lex[tid] += a;
        __syncthreads();
    }
    if (tid < BNODES) {
        int ex = lex[tid] - cnt[tid];        // exclusive
        int v = nodeBase + tid;
        if (v < N) {
            rowstart[v] = st + ex;
            dinv[v] = rsqrtf((float)(cnt[tid] + 1));
        }
        lex[tid] = ex;
    }
    __syncthreads();
    if (m <= CAP) {
        for (int i = tid; i < m; i += 1024) {
            uint2 p = pairs[st + i];
            int ld = (int)p.x - nodeBase;
            int r = atomicAdd(&lcur[ld], 1);
            lsorted[lex[ld] + r] = (int)p.y;
        }
        __syncthreads();
        for (int i = tid; i < m; i += 1024) csr[st + i] = lsorted[i];
    } else {  // overflow fallback: direct (uncoalesced) global placement
        for (int i = tid; i < m; i += 1024) {
            uint2 p = pairs[st + i];
            int ld = (int)p.x - nodeBase;
            int r = atomicAdd(&lcur[ld], 1);
            csr[st + lex[ld] + r] = (int)p.y;
        }
    }
}

// ---------- xn[v][0..15] = x[v][c]*dinv[v] (c<13), 0 pad ----------
__global__ void k_xn(const float* __restrict__ x, const float* __restrict__ dinv,
                     float* __restrict__ xn, int N) {
    int i = blockIdx.x * blockDim.x + threadIdx.x;
    if (i >= N * 16) return;
    int v = i >> 4, c = i & 15;
    xn[i] = (c < FIN) ? x[(size_t)v * FIN + c] * dinv[v] : 0.f;
}

// ---------- fused layer1: gather-agg xn -> relu(@W1+b1) -> @W2 *dinv -> y2 ----------
// 256 thr, 64 nodes/block
__global__ void k_agg1t(const float4* __restrict__ xn, const int* __restrict__ rowstart,
                        const float* __restrict__ dinv, const int* __restrict__ csr,
                        const float* __restrict__ W1, const float* __restrict__ b1,
                        const float* __restrict__ W2, float* __restrict__ y2, int N) {
    __shared__ float sW1[FIN * F1];
    __shared__ float sb1[F1];
    __shared__ float sW2[F1 * F2];
    __shared__ float sagg[64][16];
    __shared__ float sh[64][F1];
    int tid = threadIdx.x;
    for (int i = tid; i < FIN * F1; i += 256) sW1[i] = W1[i];
    for (int i = tid; i < F1 * F2; i += 256) sW2[i] = W2[i];
    if (tid < F1) sb1[tid] = b1[tid];
    int ln = tid >> 2;      // local node 0..63
    int l = tid & 3;        // float4 lane
    int base = blockIdx.x * 64;
    int v = base + ln;
    if (v < N) {
        int st = rowstart[v];
        int en = rowstart[v + 1];
        float4 acc = xn[(size_t)v * 4 + l];   // self term (xn has one dinv)
        for (int e = st; e < en; ++e) {
            int s = csr[e];
            float4 u = xn[(size_t)s * 4 + l];
            acc.x += u.x; acc.y += u.y; acc.z += u.z; acc.w += u.w;
        }
        float dv = dinv[v];
        sagg[ln][l * 4 + 0] = acc.x * dv;
        sagg[ln][l * 4 + 1] = acc.y * dv;
        sagg[ln][l * 4 + 2] = acc.z * dv;
        sagg[ln][l * 4 + 3] = acc.w * dv;
    }
    __syncthreads();
    {
        int col = tid & 63;
        int sub = tid >> 6;
        for (int nn = sub; nn < 64; nn += 4) {
            if (base + nn >= N) break;
            float acc = sb1[col];
#pragma unroll
            for (int k = 0; k < FIN; ++k) acc += sagg[nn][k] * sW1[k * F1 + col];
            sh[nn][col] = fmaxf(acc, 0.f);
        }
    }
    __syncthreads();
    {
        int ng = tid >> 5;
        int c = tid & 31;
        for (int nn = ng; nn < 64; nn += 8) {
            int v2 = base + nn;
            if (v2 >= N) break;
            float acc = 0.f;
#pragma unroll
            for (int k = 0; k < F1; ++k) acc += sh[nn][k] * sW2[k * F2 + c];
            y2[(size_t)v2 * F2 + c] = acc * dinv[v2];
        }
    }
}

// ---------- layer2 aggregate: out2 = dinv*(y2[self] + sum y2[src]) + b2 ----------
__global__ void k_agg2(const float4* __restrict__ y2, const int* __restrict__ rowstart,
                       const float* __restrict__ dinv, const int* __restrict__ csr,
                       const float* __restrict__ b2, float4* __restrict__ out2, int N) {
    int tid = threadIdx.x;
    int ln = tid >> 3;      // 0..31
    int l = tid & 7;
    int v = blockIdx.x * 32 + ln;
    if (v >= N) return;
    int st = rowstart[v];
    int en = rowstart[v + 1];
    float4 acc = y2[(size_t)v * 8 + l];
    for (int e = st; e < en; ++e) {
        int s = csr[e];
        float4 u = y2[(size_t)s * 8 + l];
        acc.x += u.x; acc.y += u.y; acc.z += u.z; acc.w += u.w;
    }
    float dv = dinv[v];
    float4 bb = ((const float4*)b2)[l];
    float4 o;
    o.x = acc.x * dv + bb.x;
    o.y = acc.y * dv + bb.y;
    o.z = acc.z * dv + bb.z;
    o.w = acc.w * dv + bb.w;
    out2[(size_t)v * 8 + l] = o;
}

// ---------- graph boundaries ----------
__global__ void k_gstart(const int* __restrict__ batch, int* __restrict__ gstart,
                         int N, int G) {
    int g = blockIdx.x * blockDim.x + threadIdx.x;
    if (g > G) return;
    int lo = 0, hi = N;
    while (lo < hi) {
        int mid = (lo + hi) >> 1;
        if (batch[mid] < g) lo = mid + 1; else hi = mid;
    }
    gstart[g] = lo;
}

// ---------- fused mean-pool + MLP ----------
__global__ void k_poolmlp(const float* __restrict__ out2, const int* __restrict__ gstart,
                          const float* __restrict__ fc1w, const float* __restrict__ fc1b,
                          const float* __restrict__ fc2w, const float* __restrict__ fc2b,
                          float* __restrict__ out, int G) {
    __shared__ float sW1[F2 * F2];
    __shared__ float sW2[F2 * F2];
    __shared__ float part[8][F2];
    __shared__ float gvec[F2];
    __shared__ float h1[F2];
    int tid = threadIdx.x;
    for (int i = tid; i < F2 * F2; i += 256) {
        sW1[i] = fc1w[i];
        sW2[i] = fc2w[i];
    }
    int g = blockIdx.x;
    int st = gstart[g], en = gstart[g + 1];
    int r = tid >> 5, c = tid & 31;
    float acc = 0.f;
    for (int v = st + r; v < en; v += 8) acc += out2[(size_t)v * F2 + c];
    part[r][c] = acc;
    __syncthreads();
    if (tid < F2) {
        float s = 0.f;
#pragma unroll
        for (int i = 0; i < 8; ++i) s += part[i][tid];
        float cnt = (float)(en - st);
        gvec[tid] = s / fmaxf(cnt, 1.0f);
    }
    __syncthreads();
    if (tid < F2) {
        float a = fc1b[tid];
#pragma unroll
        for (int k = 0; k < F2; ++k) a += gvec[k] * sW1[k * F2 + tid];
        h1[tid] = fmaxf(a, 0.f);
    }
    __syncthreads();
    if (tid < F2) {
        float a = fc2b[tid];
#pragma unroll
        for (int k = 0; k < F2; ++k) a += h1[k] * sW2[k * F2 + tid];
        out[(size_t)g * F2 + tid] = a;
    }
}

extern "C" void kernel_launch(void* const* d_in, const int* in_sizes, int n_in,
                              void* d_out, int out_size, void* d_ws, size_t ws_size,
                              hipStream_t stream) {
    const float* x    = (const float*)d_in[0];
    const int*   ei   = (const int*)d_in[1];
    const int*   batch= (const int*)d_in[2];
    const float* W1   = (const float*)d_in[3];
    const float* b1   = (const float*)d_in[4];
    const float* W2   = (const float*)d_in[5];
    const float* b2   = (const float*)d_in[6];
    const float* fc1w = (const float*)d_in[7];
    const float* fc1b = (const float*)d_in[8];
    const float* fc2w = (const float*)d_in[9];
    const float* fc2b = (const float*)d_in[10];
    float* out = (float*)d_out;

    const int N = in_sizes[0] / FIN;       // 100000
    const int E = in_sizes[1] / 2;         // 1250000
    const int G = out_size / F2;           // 512
    const int* src = ei;
    const int* dst = ei + E;
    const int NBK = (N + BNODES - 1) >> BSH;   // 196

    // ---- workspace layout (4-byte units) ----
    int* wsi = (int*)d_ws;
    int* bhist    = wsi;                   // NBK
    int* bbase    = bhist + NBK;           // NBK+1
    int* gcur     = bbase + NBK + 1;       // NBK
    int* gstart   = gcur + NBK;            // G+1
    int* rowstart = gstart + (G + 1);      // N+1
    int* csr      = rowstart + (N + 1);    // E
    size_t ioff = (size_t)(3 * NBK + 1 + G + 1 + N + 1) + E;
    ioff = (ioff + 3) & ~(size_t)3;        // 16B align
    uint2* pairs = (uint2*)(wsi + ioff);   // E uint2
    size_t foff = ioff + 2 * (size_t)E;
    float* dinv = (float*)(wsi + foff);              // N
    size_t nal = (size_t)((N + 3) & ~3);
    float* xn   = dinv + nal;                        // N*16
    float* y2   = xn + (size_t)N * 16;               // N*32
    float* out2 = y2 + (size_t)N * F2;               // N*32

    const int B = 256;
    hipMemsetAsync(bhist, 0, (size_t)NBK * sizeof(int), stream);

    hipLaunchKernelGGL(k_bhist, dim3(256), dim3(B), 0, stream, dst, bhist, E, NBK);
    hipLaunchKernelGGL(k_bscan, dim3(1), dim3(B), 0, stream,
                       bhist, bbase, gcur, rowstart, NBK, N, E);
    hipLaunchKernelGGL(k_bscatter, dim3((E + TILE - 1) / TILE), dim3(B), 0, stream,
                       src, dst, gcur, pairs, E, NBK);
    hipLaunchKernelGGL(k_bsort, dim3(NBK), dim3(1024), 0, stream,
                       pairs, bbase, rowstart, dinv, csr, N);
    hipLaunchKernelGGL(k_xn, dim3(((long)N * 16 + B - 1) / B), dim3(B), 0, stream,
                       x, dinv, xn, N);
    hipLaunchKernelGGL(k_agg1t, dim3((N + 63) / 64), dim3(B), 0, stream,
                       (const float4*)xn, rowstart, dinv, csr, W1, b1, W2, y2, N);
    hipLaunchKernelGGL(k_agg2, dim3((N + 31) / 32), dim3(B), 0, stream,
                       (const float4*)y2, rowstart, dinv, csr, b2, (float4*)out2, N);
    hipLaunchKernelGGL(k_gstart, dim3((G + 1 + B - 1) / B), dim3(B), 0, stream,
                       batch, gstart, N, G);
    hipLaunchKernelGGL(k_poolmlp, dim3(G), dim3(B), 0, stream,
                       out2, gstart, fc1w, fc1b, fc2w, fc2b, out, G);
}

// Round 7
// 159.126 us; speedup vs baseline: 3.6967x; 1.2060x over previous
//
#include <hip/hip_runtime.h>

#define F1 64
#define F2 32
#define FIN 13
#define BSH 9                 // bucket = dst >> 9  (512 nodes/bucket)
#define BNODES 512
#define TILE 8192             // edges per scatter block
#define SCT 512               // scatter threads
#define CAP 8192              // LDS sort capacity (bucket mean 6400, sd ~80)

// ---------- bucket histogram (LDS-staged) ----------
__global__ void k_bhist(const int* __restrict__ dst, int* __restrict__ bhist,
                        int E, int NBK) {
    __shared__ int lh[256];
    int tid = threadIdx.x;
    for (int i = tid; i < NBK; i += 256) lh[i] = 0;
    __syncthreads();
    int stride = gridDim.x * 256;
    for (int e = blockIdx.x * 256 + tid; e < E; e += stride)
        atomicAdd(&lh[dst[e] >> BSH], 1);
    __syncthreads();
    for (int i = tid; i < NBK; i += 256)
        if (lh[i]) atomicAdd(&bhist[i], lh[i]);
}

// ---------- scan buckets -> bbase (exclusive), init gcursor, sentinel rowstart[N]=E ----------
__global__ void k_bscan(const int* __restrict__ bhist, int* __restrict__ bbase,
                        int* __restrict__ gcur, int* __restrict__ rowstart,
                        int NBK, int N, int E) {
    __shared__ int s[256];
    int t = threadIdx.x;
    int v = (t < NBK) ? bhist[t] : 0;
    s[t] = v;
    __syncthreads();
    for (int off = 1; off < 256; off <<= 1) {
        int a = (t >= off) ? s[t - off] : 0;
        __syncthreads();
        s[t] += a;
        __syncthreads();
    }
    if (t < NBK) {
        int excl = s[t] - v;
        bbase[t] = excl;
        gcur[t] = excl;
        if (t == NBK - 1) bbase[NBK] = s[t];
    }
    if (t == 0) rowstart[N] = E;
}

// ---------- partition edges into bucket-contiguous (dst,src) pairs ----------
__global__ void __launch_bounds__(SCT)
k_bscatter(const int* __restrict__ src, const int* __restrict__ dst,
           int* __restrict__ gcur, uint2* __restrict__ pairs,
           int E, int NBK) {
    __shared__ int lh[256];
    __shared__ int lbase[256];
    int tid = threadIdx.x;
    long t0 = (long)blockIdx.x * TILE;
    int lim = (int)min((long)TILE, (long)E - t0);
    for (int i = tid; i < NBK; i += SCT) lh[i] = 0;
    __syncthreads();
    for (int i = tid; i < lim; i += SCT)
        atomicAdd(&lh[dst[t0 + i] >> BSH], 1);
    __syncthreads();
    for (int b = tid; b < NBK; b += SCT) {
        int c = lh[b];
        lbase[b] = c ? atomicAdd(&gcur[b], c) : 0;
    }
    __syncthreads();
    for (int i = tid; i < NBK; i += SCT) lh[i] = 0;
    __syncthreads();
    for (int i = tid; i < lim; i += SCT) {
        int d = dst[t0 + i];
        int b = d >> BSH;
        int r = atomicAdd(&lh[b], 1);
        pairs[lbase[b] + r] = make_uint2((unsigned)d, (unsigned)src[t0 + i]);
    }
}

// ---------- per-bucket counting sort -> csr (coalesced), rowstart, dinv ----------
__global__ void __launch_bounds__(1024)
k_bsort(const uint2* __restrict__ pairs, const int* __restrict__ bbase,
        int* __restrict__ rowstart, float* __restrict__ dinv,
        int* __restrict__ csr, int N) {
    __shared__ int cnt[BNODES];
    __shared__ int lex[BNODES];
    __shared__ int lcur[BNODES];
    __shared__ int lsorted[CAP];
    int tid = threadIdx.x;
    int bk = blockIdx.x;
    int nodeBase = bk << BSH;
    int st = bbase[bk], en = bbase[bk + 1];
    int m = en - st;
    for (int i = tid; i < BNODES; i += 1024) { cnt[i] = 0; lcur[i] = 0; }
    __syncthreads();
    for (int i = tid; i < m; i += 1024)
        atomicAdd(&cnt[(int)pairs[st + i].x - nodeBase], 1);
    __syncthreads();
    // inclusive scan of cnt -> lex (Hillis-Steele over 512)
    if (tid < BNODES) lex[tid] = cnt[tid];
    __syncthreads();
    for (int off = 1; off < BNODES; off <<= 1) {
        int a = 0;
        if (tid < BNODES && tid >= off) a = lex[tid - off];
        __syncthreads();
        if (tid < BNODES) lex[tid] += a;
        __syncthreads();
    }
    if (tid < BNODES) {
        int ex = lex[tid] - cnt[tid];        // exclusive
        int v = nodeBase + tid;
        if (v < N) {
            rowstart[v] = st + ex;
            dinv[v] = rsqrtf((float)(cnt[tid] + 1));
        }
        lex[tid] = ex;
    }
    __syncthreads();
    if (m <= CAP) {
        for (int i = tid; i < m; i += 1024) {
            uint2 p = pairs[st + i];
            int ld = (int)p.x - nodeBase;
            int r = atomicAdd(&lcur[ld], 1);
            lsorted[lex[ld] + r] = (int)p.y;
        }
        __syncthreads();
        for (int i = tid; i < m; i += 1024) csr[st + i] = lsorted[i];
    } else {  // overflow fallback: direct (uncoalesced) global placement
        for (int i = tid; i < m; i += 1024) {
            uint2 p = pairs[st + i];
            int ld = (int)p.x - nodeBase;
            int r = atomicAdd(&lcur[ld], 1);
            csr[st + lex[ld] + r] = (int)p.y;
        }
    }
}

// ---------- xn[v][0..15] = x[v][c]*dinv[v] (c<13), 0 pad ----------
__global__ void k_xn(const float* __restrict__ x, const float* __restrict__ dinv,
                     float* __restrict__ xn, int N) {
    int i = blockIdx.x * blockDim.x + threadIdx.x;
    if (i >= N * 16) return;
    int v = i >> 4, c = i & 15;
    xn[i] = (c < FIN) ? x[(size_t)v * FIN + c] * dinv[v] : 0.f;
}

// ---------- fused layer1: gather-agg xn -> relu(@W1+b1) -> @W2 *dinv -> y2 ----------
// 256 thr, 64 nodes/block
__global__ void k_agg1t(const float4* __restrict__ xn, const int* __restrict__ rowstart,
                        const float* __restrict__ dinv, const int* __restrict__ csr,
                        const float* __restrict__ W1, const float* __restrict__ b1,
                        const float* __restrict__ W2, float* __restrict__ y2, int N) {
    __shared__ float sW1[FIN * F1];
    __shared__ float sb1[F1];
    __shared__ float sW2[F1 * F2];
    __shared__ float sagg[64][16];
    __shared__ float sh[64][F1];
    int tid = threadIdx.x;
    for (int i = tid; i < FIN * F1; i += 256) sW1[i] = W1[i];
    for (int i = tid; i < F1 * F2; i += 256) sW2[i] = W2[i];
    if (tid < F1) sb1[tid] = b1[tid];
    int ln = tid >> 2;      // local node 0..63
    int l = tid & 3;        // float4 lane
    int base = blockIdx.x * 64;
    int v = base + ln;
    if (v < N) {
        int st = rowstart[v];
        int en = rowstart[v + 1];
        float4 acc = xn[(size_t)v * 4 + l];   // self term (xn has one dinv)
        for (int e = st; e < en; ++e) {
            int s = csr[e];
            float4 u = xn[(size_t)s * 4 + l];
            acc.x += u.x; acc.y += u.y; acc.z += u.z; acc.w += u.w;
        }
        float dv = dinv[v];
        sagg[ln][l * 4 + 0] = acc.x * dv;
        sagg[ln][l * 4 + 1] = acc.y * dv;
        sagg[ln][l * 4 + 2] = acc.z * dv;
        sagg[ln][l * 4 + 3] = acc.w * dv;
    }
    __syncthreads();
    {
        int col = tid & 63;
        int sub = tid >> 6;
        for (int nn = sub; nn < 64; nn += 4) {
            if (base + nn >= N) break;
            float acc = sb1[col];
#pragma unroll
            for (int k = 0; k < FIN; ++k) acc += sagg[nn][k] * sW1[k * F1 + col];
            sh[nn][col] = fmaxf(acc, 0.f);
        }
    }
    __syncthreads();
    {
        int ng = tid >> 5;
        int c = tid & 31;
        for (int nn = ng; nn < 64; nn += 8) {
            int v2 = base + nn;
            if (v2 >= N) break;
            float acc = 0.f;
#pragma unroll
            for (int k = 0; k < F1; ++k) acc += sh[nn][k] * sW2[k * F2 + c];
            y2[(size_t)v2 * F2 + c] = acc * dinv[v2];
        }
    }
}

// ---------- layer2 aggregate: out2 = dinv*(y2[self] + sum y2[src]) + b2 ----------
__global__ void k_agg2(const float4* __restrict__ y2, const int* __restrict__ rowstart,
                       const float* __restrict__ dinv, const int* __restrict__ csr,
                       const float* __restrict__ b2, float4* __restrict__ out2, int N) {
    int tid = threadIdx.x;
    int ln = tid >> 3;      // 0..31
    int l = tid & 7;
    int v = blockIdx.x * 32 + ln;
    if (v >= N) return;
    int st = rowstart[v];
    int en = rowstart[v + 1];
    float4 acc = y2[(size_t)v * 8 + l];
    for (int e = st; e < en; ++e) {
        int s = csr[e];
        float4 u = y2[(size_t)s * 8 + l];
        acc.x += u.x; acc.y += u.y; acc.z += u.z; acc.w += u.w;
    }
    float dv = dinv[v];
    float4 bb = ((const float4*)b2)[l];
    float4 o;
    o.x = acc.x * dv + bb.x;
    o.y = acc.y * dv + bb.y;
    o.z = acc.z * dv + bb.z;
    o.w = acc.w * dv + bb.w;
    out2[(size_t)v * 8 + l] = o;
}

// ---------- fused mean-pool + MLP (graph bounds via binary search) ----------
__global__ void k_poolmlp(const float* __restrict__ out2, const int* __restrict__ batch,
                          const float* __restrict__ fc1w, const float* __restrict__ fc1b,
                          const float* __restrict__ fc2w, const float* __restrict__ fc2b,
                          float* __restrict__ out, int N, int G) {
    __shared__ float sW1[F2 * F2];
    __shared__ float sW2[F2 * F2];
    __shared__ float part[8][F2];
    __shared__ float gvec[F2];
    __shared__ float h1[F2];
    __shared__ int bounds[2];
    int tid = threadIdx.x;
    for (int i = tid; i < F2 * F2; i += 256) {
        sW1[i] = fc1w[i];
        sW2[i] = fc2w[i];
    }
    int g = blockIdx.x;
    if (tid < 2) {
        int target = g + tid;          // lower_bound(batch, target)
        int lo = 0, hi = N;
        while (lo < hi) {
            int mid = (lo + hi) >> 1;
            if (batch[mid] < target) lo = mid + 1; else hi = mid;
        }
        bounds[tid] = lo;
    }
    __syncthreads();
    int st = bounds[0], en = bounds[1];
    int r = tid >> 5, c = tid & 31;
    float acc = 0.f;
    for (int v = st + r; v < en; v += 8) acc += out2[(size_t)v * F2 + c];
    part[r][c] = acc;
    __syncthreads();
    if (tid < F2) {
        float s = 0.f;
#pragma unroll
        for (int i = 0; i < 8; ++i) s += part[i][tid];
        float cnt = (float)(en - st);
        gvec[tid] = s / fmaxf(cnt, 1.0f);
    }
    __syncthreads();
    if (tid < F2) {
        float a = fc1b[tid];
#pragma unroll
        for (int k = 0; k < F2; ++k) a += gvec[k] * sW1[k * F2 + tid];
        h1[tid] = fmaxf(a, 0.f);
    }
    __syncthreads();
    if (tid < F2) {
        float a = fc2b[tid];
#pragma unroll
        for (int k = 0; k < F2; ++k) a += h1[k] * sW2[k * F2 + tid];
        out[(size_t)g * F2 + tid] = a;
    }
}

extern "C" void kernel_launch(void* const* d_in, const int* in_sizes, int n_in,
                              void* d_out, int out_size, void* d_ws, size_t ws_size,
                              hipStream_t stream) {
    const float* x    = (const float*)d_in[0];
    const int*   ei   = (const int*)d_in[1];
    const int*   batch= (const int*)d_in[2];
    const float* W1   = (const float*)d_in[3];
    const float* b1   = (const float*)d_in[4];
    const float* W2   = (const float*)d_in[5];
    const float* b2   = (const float*)d_in[6];
    const float* fc1w = (const float*)d_in[7];
    const float* fc1b = (const float*)d_in[8];
    const float* fc2w = (const float*)d_in[9];
    const float* fc2b = (const float*)d_in[10];
    float* out = (float*)d_out;

    const int N = in_sizes[0] / FIN;       // 100000
    const int E = in_sizes[1] / 2;         // 1250000
    const int G = out_size / F2;           // 512
    const int* src = ei;
    const int* dst = ei + E;
    const int NBK = (N + BNODES - 1) >> BSH;   // 196

    // ---- workspace layout (4-byte units) ----
    int* wsi = (int*)d_ws;
    int* bhist    = wsi;                   // NBK
    int* bbase    = bhist + NBK;           // NBK+1
    int* gcur     = bbase + NBK + 1;       // NBK
    int* rowstart = gcur + NBK;            // N+1
    int* csr      = rowstart + (N + 1);    // E
    size_t ioff = (size_t)(3 * NBK + 1 + N + 1) + E;
    ioff = (ioff + 3) & ~(size_t)3;        // 16B align
    uint2* pairs = (uint2*)(wsi + ioff);   // E uint2
    size_t foff = ioff + 2 * (size_t)E;
    float* dinv = (float*)(wsi + foff);              // N
    size_t nal = (size_t)((N + 3) & ~3);
    float* xn   = dinv + nal;                        // N*16
    float* y2   = xn + (size_t)N * 16;               // N*32
    float* out2 = y2 + (size_t)N * F2;               // N*32

    const int B = 256;
    hipMemsetAsync(bhist, 0, (size_t)NBK * sizeof(int), stream);

    hipLaunchKernelGGL(k_bhist, dim3(256), dim3(B), 0, stream, dst, bhist, E, NBK);
    hipLaunchKernelGGL(k_bscan, dim3(1), dim3(B), 0, stream,
                       bhist, bbase, gcur, rowstart, NBK, N, E);
    hipLaunchKernelGGL(k_bscatter, dim3((E + TILE - 1) / TILE), dim3(SCT), 0, stream,
                       src, dst, gcur, pairs, E, NBK);
    hipLaunchKernelGGL(k_bsort, dim3(NBK), dim3(1024), 0, stream,
                       pairs, bbase, rowstart, dinv, csr, N);
    hipLaunchKernelGGL(k_xn, dim3(((long)N * 16 + B - 1) / B), dim3(B), 0, stream,
                       x, dinv, xn, N);
    hipLaunchKernelGGL(k_agg1t, dim3((N + 63) / 64), dim3(B), 0, stream,
                       (const float4*)xn, rowstart, dinv, csr, W1, b1, W2, y2, N);
    hipLaunchKernelGGL(k_agg2, dim3((N + 31) / 32), dim3(B), 0, stream,
                       (const float4*)y2, rowstart, dinv, csr, b2, (float4*)out2, N);
    hipLaunchKernelGGL(k_poolmlp, dim3(G), dim3(B), 0, stream,
                       out2, batch, fc1w, fc1b, fc2w, fc2b, out, N, G);
}

// Round 8
// 149.746 us; speedup vs baseline: 3.9282x; 1.0626x over previous
//
#include <hip/hip_runtime.h>

#define F1 64
#define F2 32
#define FIN 13
#define BSH 9                 // bucket = dst >> 9  (512 nodes/bucket)
#define BNODES 512
#define TILE 4096             // edges per scatter block
#define SCT 256               // scatter threads
#define CAP 8192              // LDS sort capacity (bucket mean 6400, sd ~80)

// ---------- bucket histogram (LDS-staged) ----------
__global__ void k_bhist(const int* __restrict__ dst, int* __restrict__ bhist,
                        int E, int NBK) {
    __shared__ int lh[256];
    int tid = threadIdx.x;
    for (int i = tid; i < NBK; i += 256) lh[i] = 0;
    __syncthreads();
    int stride = gridDim.x * 256;
    for (int e = blockIdx.x * 256 + tid; e < E; e += stride)
        atomicAdd(&lh[dst[e] >> BSH], 1);
    __syncthreads();
    for (int i = tid; i < NBK; i += 256)
        if (lh[i]) atomicAdd(&bhist[i], lh[i]);
}

// ---------- scan buckets -> bbase (exclusive), init gcursor, sentinel rowstart[N]=E ----------
__global__ void k_bscan(const int* __restrict__ bhist, int* __restrict__ bbase,
                        int* __restrict__ gcur, int* __restrict__ rowstart,
                        int NBK, int N, int E) {
    __shared__ int s[256];
    int t = threadIdx.x;
    int v = (t < NBK) ? bhist[t] : 0;
    s[t] = v;
    __syncthreads();
    for (int off = 1; off < 256; off <<= 1) {
        int a = (t >= off) ? s[t - off] : 0;
        __syncthreads();
        s[t] += a;
        __syncthreads();
    }
    if (t < NBK) {
        int excl = s[t] - v;
        bbase[t] = excl;
        gcur[t] = excl;
        if (t == NBK - 1) bbase[NBK] = s[t];
    }
    if (t == 0) rowstart[N] = E;
}

// ---------- partition edges into bucket-contiguous (dst,src) pairs ----------
__global__ void __launch_bounds__(SCT)
k_bscatter(const int* __restrict__ src, const int* __restrict__ dst,
           int* __restrict__ gcur, uint2* __restrict__ pairs,
           int E, int NBK) {
    __shared__ int lh[256];
    __shared__ int lbase[256];
    int tid = threadIdx.x;
    long t0 = (long)blockIdx.x * TILE;
    int lim = (int)min((long)TILE, (long)E - t0);
    for (int i = tid; i < NBK; i += SCT) lh[i] = 0;
    __syncthreads();
    for (int i = tid; i < lim; i += SCT)
        atomicAdd(&lh[dst[t0 + i] >> BSH], 1);
    __syncthreads();
    for (int b = tid; b < NBK; b += SCT) {
        int c = lh[b];
        lbase[b] = c ? atomicAdd(&gcur[b], c) : 0;
    }
    __syncthreads();
    for (int i = tid; i < NBK; i += SCT) lh[i] = 0;
    __syncthreads();
    for (int i = tid; i < lim; i += SCT) {
        int d = dst[t0 + i];
        int b = d >> BSH;
        int r = atomicAdd(&lh[b], 1);
        pairs[lbase[b] + r] = make_uint2((unsigned)d, (unsigned)src[t0 + i]);
    }
}

// ---------- per-bucket counting sort -> csr (coalesced), rowstart, dinv ----------
__global__ void __launch_bounds__(1024)
k_bsort(const uint2* __restrict__ pairs, const int* __restrict__ bbase,
        int* __restrict__ rowstart, float* __restrict__ dinv,
        int* __restrict__ csr, int N) {
    __shared__ int cnt[BNODES];
    __shared__ int lex[BNODES];
    __shared__ int lcur[BNODES];
    __shared__ int lsorted[CAP];
    int tid = threadIdx.x;
    int bk = blockIdx.x;
    int nodeBase = bk << BSH;
    int st = bbase[bk], en = bbase[bk + 1];
    int m = en - st;
    for (int i = tid; i < BNODES; i += 1024) { cnt[i] = 0; lcur[i] = 0; }
    __syncthreads();
    for (int i = tid; i < m; i += 1024)
        atomicAdd(&cnt[(int)pairs[st + i].x - nodeBase], 1);
    __syncthreads();
    if (tid < BNODES) lex[tid] = cnt[tid];
    __syncthreads();
    for (int off = 1; off < BNODES; off <<= 1) {
        int a = 0;
        if (tid < BNODES && tid >= off) a = lex[tid - off];
        __syncthreads();
        if (tid < BNODES) lex[tid] += a;
        __syncthreads();
    }
    if (tid < BNODES) {
        int ex = lex[tid] - cnt[tid];        // exclusive
        int v = nodeBase + tid;
        if (v < N) {
            rowstart[v] = st + ex;
            dinv[v] = rsqrtf((float)(cnt[tid] + 1));
        }
        lex[tid] = ex;
    }
    __syncthreads();
    if (m <= CAP) {
        for (int i = tid; i < m; i += 1024) {
            uint2 p = pairs[st + i];
            int ld = (int)p.x - nodeBase;
            int r = atomicAdd(&lcur[ld], 1);
            lsorted[lex[ld] + r] = (int)p.y;
        }
        __syncthreads();
        for (int i = tid; i < m; i += 1024) csr[st + i] = lsorted[i];
    } else {
        for (int i = tid; i < m; i += 1024) {
            uint2 p = pairs[st + i];
            int ld = (int)p.x - nodeBase;
            int r = atomicAdd(&lcur[ld], 1);
            csr[st + lex[ld] + r] = (int)p.y;
        }
    }
}

// ---------- xn[v][0..15] = x[v][c]*dinv[v] (c<13), 0 pad ----------
__global__ void k_xn(const float* __restrict__ x, const float* __restrict__ dinv,
                     float* __restrict__ xn, int N) {
    int i = blockIdx.x * blockDim.x + threadIdx.x;
    if (i >= N * 16) return;
    int v = i >> 4, c = i & 15;
    xn[i] = (c < FIN) ? x[(size_t)v * FIN + c] * dinv[v] : 0.f;
}

// ---------- fused layer1: gather-agg xn (4 edge-slots/node) -> relu(@W1+b1) -> @W2 *dinv -> y2 ----------
// 512 thr = 32 nodes x (4 slots x 4 col-lanes)
__global__ void __launch_bounds__(512)
k_agg1t(const float4* __restrict__ xn, const int* __restrict__ rowstart,
        const float* __restrict__ dinv, const int* __restrict__ csr,
        const float* __restrict__ W1, const float* __restrict__ b1,
        const float* __restrict__ W2, float* __restrict__ y2, int N) {
    __shared__ float sW1[FIN * F1];
    __shared__ float sb1[F1];
    __shared__ float sW2[F1 * F2];
    __shared__ float sagg[32][16];
    __shared__ float sh[32][F1];
    int tid = threadIdx.x;
    for (int i = tid; i < FIN * F1; i += 512) sW1[i] = W1[i];
    for (int i = tid; i < F1 * F2; i += 512) sW2[i] = W2[i];
    if (tid < F1) sb1[tid] = b1[tid];
    int ln = tid >> 4;           // local node 0..31
    int slot = (tid >> 2) & 3;   // edge slot 0..3
    int l = tid & 3;             // float4 col-lane
    int base = blockIdx.x * 32;
    int v = base + ln;
    float4 acc = make_float4(0.f, 0.f, 0.f, 0.f);
    if (v < N) {
        int st = rowstart[v];
        int en = rowstart[v + 1];
        for (int e = st + slot; e < en; e += 4) {
            int s = csr[e];
            float4 u = xn[(size_t)s * 4 + l];
            acc.x += u.x; acc.y += u.y; acc.z += u.z; acc.w += u.w;
        }
    }
    // reduce 4 slots (lane xor 4, 8 within 16-thread node group)
    acc.x += __shfl_xor(acc.x, 4); acc.y += __shfl_xor(acc.y, 4);
    acc.z += __shfl_xor(acc.z, 4); acc.w += __shfl_xor(acc.w, 4);
    acc.x += __shfl_xor(acc.x, 8); acc.y += __shfl_xor(acc.y, 8);
    acc.z += __shfl_xor(acc.z, 8); acc.w += __shfl_xor(acc.w, 8);
    if (v < N && slot == 0) {
        float4 s4 = xn[(size_t)v * 4 + l];   // self term (xn has one dinv)
        float dv = dinv[v];
        sagg[ln][l * 4 + 0] = (s4.x + acc.x) * dv;
        sagg[ln][l * 4 + 1] = (s4.y + acc.y) * dv;
        sagg[ln][l * 4 + 2] = (s4.z + acc.z) * dv;
        sagg[ln][l * 4 + 3] = (s4.w + acc.w) * dv;
    }
    __syncthreads();
    {
        int col = tid & 63;
        int sub = tid >> 6;      // 0..7
        for (int nn = sub; nn < 32; nn += 8) {
            if (base + nn >= N) break;
            float acc1 = sb1[col];
#pragma unroll
            for (int k = 0; k < FIN; ++k) acc1 += sagg[nn][k] * sW1[k * F1 + col];
            sh[nn][col] = fmaxf(acc1, 0.f);
        }
    }
    __syncthreads();
    {
        int ng = tid >> 5;       // 0..15
        int c = tid & 31;
        for (int nn = ng; nn < 32; nn += 16) {
            int v2 = base + nn;
            if (v2 >= N) break;
            float acc2 = 0.f;
#pragma unroll
            for (int k = 0; k < F1; ++k) acc2 += sh[nn][k] * sW2[k * F2 + c];
            y2[(size_t)v2 * F2 + c] = acc2 * dinv[v2];
        }
    }
}

// ---------- layer2 aggregate (4 edge-slots/node): out2 = dinv*(y2[self]+sum y2[src]) + b2 ----------
// 512 thr = 16 nodes x (4 slots x 8 lanes)
__global__ void __launch_bounds__(512)
k_agg2(const float4* __restrict__ y2, const int* __restrict__ rowstart,
       const float* __restrict__ dinv, const int* __restrict__ csr,
       const float* __restrict__ b2, float4* __restrict__ out2, int N) {
    int tid = threadIdx.x;
    int ln = tid >> 5;           // local node 0..15
    int slot = (tid >> 3) & 3;   // edge slot 0..3
    int l = tid & 7;             // float4 lane (8 x 16B = 128B row)
    int v = blockIdx.x * 16 + ln;
    if (v >= N) return;
    int st = rowstart[v];
    int en = rowstart[v + 1];
    float4 acc = make_float4(0.f, 0.f, 0.f, 0.f);
    for (int e = st + slot; e < en; e += 4) {
        int s = csr[e];
        float4 u = y2[(size_t)s * 8 + l];
        acc.x += u.x; acc.y += u.y; acc.z += u.z; acc.w += u.w;
    }
    // reduce 4 slots (lane xor 8, 16 within 32-thread node group)
    acc.x += __shfl_xor(acc.x, 8);  acc.y += __shfl_xor(acc.y, 8);
    acc.z += __shfl_xor(acc.z, 8);  acc.w += __shfl_xor(acc.w, 8);
    acc.x += __shfl_xor(acc.x, 16); acc.y += __shfl_xor(acc.y, 16);
    acc.z += __shfl_xor(acc.z, 16); acc.w += __shfl_xor(acc.w, 16);
    if (slot == 0) {
        float4 s4 = y2[(size_t)v * 8 + l];
        float dv = dinv[v];
        float4 bb = ((const float4*)b2)[l];
        float4 o;
        o.x = (s4.x + acc.x) * dv + bb.x;
        o.y = (s4.y + acc.y) * dv + bb.y;
        o.z = (s4.z + acc.z) * dv + bb.z;
        o.w = (s4.w + acc.w) * dv + bb.w;
        out2[(size_t)v * 8 + l] = o;
    }
}

// ---------- fused mean-pool + MLP (graph bounds via binary search) ----------
__global__ void k_poolmlp(const float* __restrict__ out2, const int* __restrict__ batch,
                          const float* __restrict__ fc1w, const float* __restrict__ fc1b,
                          const float* __restrict__ fc2w, const float* __restrict__ fc2b,
                          float* __restrict__ out, int N, int G) {
    __shared__ float sW1[F2 * F2];
    __shared__ float sW2[F2 * F2];
    __shared__ float part[8][F2];
    __shared__ float gvec[F2];
    __shared__ float h1[F2];
    __shared__ int bounds[2];
    int tid = threadIdx.x;
    for (int i = tid; i < F2 * F2; i += 256) {
        sW1[i] = fc1w[i];
        sW2[i] = fc2w[i];
    }
    int g = blockIdx.x;
    if (tid < 2) {
        int target = g + tid;
        int lo = 0, hi = N;
        while (lo < hi) {
            int mid = (lo + hi) >> 1;
            if (batch[mid] < target) lo = mid + 1; else hi = mid;
        }
        bounds[tid] = lo;
    }
    __syncthreads();
    int st = bounds[0], en = bounds[1];
    int r = tid >> 5, c = tid & 31;
    float acc = 0.f;
    for (int v = st + r; v < en; v += 8) acc += out2[(size_t)v * F2 + c];
    part[r][c] = acc;
    __syncthreads();
    if (tid < F2) {
        float s = 0.f;
#pragma unroll
        for (int i = 0; i < 8; ++i) s += part[i][tid];
        float cnt = (float)(en - st);
        gvec[tid] = s / fmaxf(cnt, 1.0f);
    }
    __syncthreads();
    if (tid < F2) {
        float a = fc1b[tid];
#pragma unroll
        for (int k = 0; k < F2; ++k) a += gvec[k] * sW1[k * F2 + tid];
        h1[tid] = fmaxf(a, 0.f);
    }
    __syncthreads();
    if (tid < F2) {
        float a = fc2b[tid];
#pragma unroll
        for (int k = 0; k < F2; ++k) a += h1[k] * sW2[k * F2 + tid];
        out[(size_t)g * F2 + tid] = a;
    }
}

extern "C" void kernel_launch(void* const* d_in, const int* in_sizes, int n_in,
                              void* d_out, int out_size, void* d_ws, size_t ws_size,
                              hipStream_t stream) {
    const float* x    = (const float*)d_in[0];
    const int*   ei   = (const int*)d_in[1];
    const int*   batch= (const int*)d_in[2];
    const float* W1   = (const float*)d_in[3];
    const float* b1   = (const float*)d_in[4];
    const float* W2   = (const float*)d_in[5];
    const float* b2   = (const float*)d_in[6];
    const float* fc1w = (const float*)d_in[7];
    const float* fc1b = (const float*)d_in[8];
    const float* fc2w = (const float*)d_in[9];
    const float* fc2b = (const float*)d_in[10];
    float* out = (float*)d_out;

    const int N = in_sizes[0] / FIN;       // 100000
    const int E = in_sizes[1] / 2;         // 1250000
    const int G = out_size / F2;           // 512
    const int* src = ei;
    const int* dst = ei + E;
    const int NBK = (N + BNODES - 1) >> BSH;   // 196

    // ---- workspace layout (4-byte units) ----
    int* wsi = (int*)d_ws;
    int* bhist    = wsi;                   // NBK
    int* bbase    = bhist + NBK;           // NBK+1
    int* gcur     = bbase + NBK + 1;       // NBK
    int* rowstart = gcur + NBK;            // N+1
    int* csr      = rowstart + (N + 1);    // E
    size_t ioff = (size_t)(3 * NBK + 1 + N + 1) + E;
    ioff = (ioff + 3) & ~(size_t)3;        // 16B align
    uint2* pairs = (uint2*)(wsi + ioff);   // E uint2
    size_t foff = ioff + 2 * (size_t)E;
    float* dinv = (float*)(wsi + foff);              // N
    size_t nal = (size_t)((N + 3) & ~3);
    float* xn   = dinv + nal;                        // N*16
    float* y2   = xn + (size_t)N * 16;               // N*32
    float* out2 = y2 + (size_t)N * F2;               // N*32

    const int B = 256;
    hipMemsetAsync(bhist, 0, (size_t)NBK * sizeof(int), stream);

    hipLaunchKernelGGL(k_bhist, dim3(256), dim3(B), 0, stream, dst, bhist, E, NBK);
    hipLaunchKernelGGL(k_bscan, dim3(1), dim3(B), 0, stream,
                       bhist, bbase, gcur, rowstart, NBK, N, E);
    hipLaunchKernelGGL(k_bscatter, dim3((E + TILE - 1) / TILE), dim3(SCT), 0, stream,
                       src, dst, gcur, pairs, E, NBK);
    hipLaunchKernelGGL(k_bsort, dim3(NBK), dim3(1024), 0, stream,
                       pairs, bbase, rowstart, dinv, csr, N);
    hipLaunchKernelGGL(k_xn, dim3(((long)N * 16 + B - 1) / B), dim3(B), 0, stream,
                       x, dinv, xn, N);
    hipLaunchKernelGGL(k_agg1t, dim3((N + 31) / 32), dim3(512), 0, stream,
                       (const float4*)xn, rowstart, dinv, csr, W1, b1, W2, y2, N);
    hipLaunchKernelGGL(k_agg2, dim3((N + 15) / 16), dim3(512), 0, stream,
                       (const float4*)y2, rowstart, dinv, csr, b2, (float4*)out2, N);
    hipLaunchKernelGGL(k_poolmlp, dim3(G), dim3(B), 0, stream,
                       out2, batch, fc1w, fc1b, fc2w, fc2b, out, N, G);
}

// Round 9
// 145.545 us; speedup vs baseline: 4.0416x; 1.0289x over previous
//
#include <hip/hip_runtime.h>
#include <hip/hip_fp16.h>

#define F1 64
#define F2 32
#define FIN 13
#define BSH 9                 // bucket = dst >> 9  (512 nodes/bucket)
#define BNODES 512
#define TILE 4096             // edges per scatter block
#define SCT 256               // scatter threads
#define CAP 8192              // LDS sort capacity (bucket mean 6400, sd ~80)
#define SRCMASK 0x7FFFFF      // 23-bit src (N < 8.4M)

// ---------- bucket histogram (LDS-staged) ----------
__global__ void k_bhist(const int* __restrict__ dst, int* __restrict__ bhist,
                        int E, int NBK) {
    __shared__ int lh[256];
    int tid = threadIdx.x;
    for (int i = tid; i < NBK; i += 256) lh[i] = 0;
    __syncthreads();
    int stride = gridDim.x * 256;
    for (int e = blockIdx.x * 256 + tid; e < E; e += stride)
        atomicAdd(&lh[dst[e] >> BSH], 1);
    __syncthreads();
    for (int i = tid; i < NBK; i += 256)
        if (lh[i]) atomicAdd(&bhist[i], lh[i]);
}

// ---------- scan buckets -> bbase (exclusive), init gcursor, sentinel rowstart[N]=E ----------
__global__ void k_bscan(const int* __restrict__ bhist, int* __restrict__ bbase,
                        int* __restrict__ gcur, int* __restrict__ rowstart,
                        int NBK, int N, int E) {
    __shared__ int s[256];
    int t = threadIdx.x;
    int v = (t < NBK) ? bhist[t] : 0;
    s[t] = v;
    __syncthreads();
    for (int off = 1; off < 256; off <<= 1) {
        int a = (t >= off) ? s[t - off] : 0;
        __syncthreads();
        s[t] += a;
        __syncthreads();
    }
    if (t < NBK) {
        int excl = s[t] - v;
        bbase[t] = excl;
        gcur[t] = excl;
        if (t == NBK - 1) bbase[NBK] = s[t];
    }
    if (t == 0) rowstart[N] = E;
}

// ---------- partition edges into bucket-contiguous packed (ldst<<23|src) ----------
__global__ void __launch_bounds__(SCT)
k_bscatter(const int* __restrict__ src, const int* __restrict__ dst,
           int* __restrict__ gcur, unsigned* __restrict__ pairs,
           int E, int NBK) {
    __shared__ int lh[256];
    __shared__ int lbase[256];
    int tid = threadIdx.x;
    long t0 = (long)blockIdx.x * TILE;
    int lim = (int)min((long)TILE, (long)E - t0);
    for (int i = tid; i < NBK; i += SCT) lh[i] = 0;
    __syncthreads();
    for (int i = tid; i < lim; i += SCT)
        atomicAdd(&lh[dst[t0 + i] >> BSH], 1);
    __syncthreads();
    for (int b = tid; b < NBK; b += SCT) {
        int c = lh[b];
        lbase[b] = c ? atomicAdd(&gcur[b], c) : 0;
    }
    __syncthreads();
    for (int i = tid; i < NBK; i += SCT) lh[i] = 0;
    __syncthreads();
    for (int i = tid; i < lim; i += SCT) {
        int d = dst[t0 + i];
        int b = d >> BSH;
        int r = atomicAdd(&lh[b], 1);
        pairs[lbase[b] + r] = ((unsigned)(d & (BNODES - 1)) << 23) | (unsigned)src[t0 + i];
    }
}

// ---------- per-bucket counting sort -> csr (coalesced), rowstart, dinv ----------
__global__ void __launch_bounds__(1024)
k_bsort(const unsigned* __restrict__ pairs, const int* __restrict__ bbase,
        int* __restrict__ rowstart, float* __restrict__ dinv,
        int* __restrict__ csr, int N) {
    __shared__ int cnt[BNODES];
    __shared__ int lex[BNODES];
    __shared__ int lcur[BNODES];
    __shared__ int lsorted[CAP];
    int tid = threadIdx.x;
    int bk = blockIdx.x;
    int nodeBase = bk << BSH;
    int st = bbase[bk], en = bbase[bk + 1];
    int m = en - st;
    for (int i = tid; i < BNODES; i += 1024) { cnt[i] = 0; lcur[i] = 0; }
    __syncthreads();
    for (int i = tid; i < m; i += 1024)
        atomicAdd(&cnt[pairs[st + i] >> 23], 1);
    __syncthreads();
    if (tid < BNODES) lex[tid] = cnt[tid];
    __syncthreads();
    for (int off = 1; off < BNODES; off <<= 1) {
        int a = 0;
        if (tid < BNODES && tid >= off) a = lex[tid - off];
        __syncthreads();
        if (tid < BNODES) lex[tid] += a;
        __syncthreads();
    }
    if (tid < BNODES) {
        int ex = lex[tid] - cnt[tid];        // exclusive
        int v = nodeBase + tid;
        if (v < N) {
            rowstart[v] = st + ex;
            dinv[v] = rsqrtf((float)(cnt[tid] + 1));
        }
        lex[tid] = ex;
    }
    __syncthreads();
    if (m <= CAP) {
        for (int i = tid; i < m; i += 1024) {
            unsigned p = pairs[st + i];
            int ld = p >> 23;
            int r = atomicAdd(&lcur[ld], 1);
            lsorted[lex[ld] + r] = (int)(p & SRCMASK);
        }
        __syncthreads();
        for (int i = tid; i < m; i += 1024) csr[st + i] = lsorted[i];
    } else {
        for (int i = tid; i < m; i += 1024) {
            unsigned p = pairs[st + i];
            int ld = p >> 23;
            int r = atomicAdd(&lcur[ld], 1);
            csr[st + lex[ld] + r] = (int)(p & SRCMASK);
        }
    }
}

// ---------- xnh[v][cp] = half2(x[v][2cp], x[v][2cp+1]) * dinv  (16 cols, 0 pad) ----------
__global__ void k_xn(const float* __restrict__ x, const float* __restrict__ dinv,
                     __half2* __restrict__ xnh, int N) {
    int i = blockIdx.x * blockDim.x + threadIdx.x;
    if (i >= N * 8) return;
    int v = i >> 3, cp = i & 7;
    int c0 = cp * 2, c1 = cp * 2 + 1;
    float dv = dinv[v];
    float a = (c0 < FIN) ? x[(size_t)v * FIN + c0] * dv : 0.f;
    float b = (c1 < FIN) ? x[(size_t)v * FIN + c1] * dv : 0.f;
    xnh[i] = __floats2half2_rn(a, b);
}

// ---------- fused layer1: gather-agg fp16 xn (4 slots/node) -> relu(@W1+b1) -> @W2 *dinv -> fp16 y2 ----------
// 512 thr = 32 nodes x (4 slots x 4 col-lanes); lane reads 8B (4 fp16 cols)
__global__ void __launch_bounds__(512)
k_agg1t(const uint2* __restrict__ xnh, const int* __restrict__ rowstart,
        const float* __restrict__ dinv, const int* __restrict__ csr,
        const float* __restrict__ W1, const float* __restrict__ b1,
        const float* __restrict__ W2, __half2* __restrict__ y2h, int N) {
    __shared__ float sW1[FIN * F1];
    __shared__ float sb1[F1];
    __shared__ float sW2[F1 * F2];
    __shared__ float sagg[32][16];
    __shared__ float sh[32][F1];
    int tid = threadIdx.x;
    for (int i = tid; i < FIN * F1; i += 512) sW1[i] = W1[i];
    for (int i = tid; i < F1 * F2; i += 512) sW2[i] = W2[i];
    if (tid < F1) sb1[tid] = b1[tid];
    int ln = tid >> 4;           // local node 0..31
    int slot = (tid >> 2) & 3;   // edge slot 0..3
    int l = tid & 3;             // col-lane: cols 4l..4l+3
    int base = blockIdx.x * 32;
    int v = base + ln;
    float4 acc = make_float4(0.f, 0.f, 0.f, 0.f);
    if (v < N) {
        int st = rowstart[v];
        int en = rowstart[v + 1];
        for (int e = st + slot; e < en; e += 4) {
            int s = csr[e];
            uint2 u = xnh[(size_t)s * 4 + l];
            float2 f0 = __half22float2(*reinterpret_cast<__half2*>(&u.x));
            float2 f1 = __half22float2(*reinterpret_cast<__half2*>(&u.y));
            acc.x += f0.x; acc.y += f0.y; acc.z += f1.x; acc.w += f1.y;
        }
    }
    acc.x += __shfl_xor(acc.x, 4); acc.y += __shfl_xor(acc.y, 4);
    acc.z += __shfl_xor(acc.z, 4); acc.w += __shfl_xor(acc.w, 4);
    acc.x += __shfl_xor(acc.x, 8); acc.y += __shfl_xor(acc.y, 8);
    acc.z += __shfl_xor(acc.z, 8); acc.w += __shfl_xor(acc.w, 8);
    if (v < N && slot == 0) {
        uint2 u = xnh[(size_t)v * 4 + l];   // self (has one dinv)
        float2 f0 = __half22float2(*reinterpret_cast<__half2*>(&u.x));
        float2 f1 = __half22float2(*reinterpret_cast<__half2*>(&u.y));
        float dv = dinv[v];
        sagg[ln][l * 4 + 0] = (f0.x + acc.x) * dv;
        sagg[ln][l * 4 + 1] = (f0.y + acc.y) * dv;
        sagg[ln][l * 4 + 2] = (f1.x + acc.z) * dv;
        sagg[ln][l * 4 + 3] = (f1.y + acc.w) * dv;
    }
    __syncthreads();
    {
        int col = tid & 63;
        int sub = tid >> 6;      // 0..7
        for (int nn = sub; nn < 32; nn += 8) {
            if (base + nn >= N) break;
            float acc1 = sb1[col];
#pragma unroll
            for (int k = 0; k < FIN; ++k) acc1 += sagg[nn][k] * sW1[k * F1 + col];
            sh[nn][col] = fmaxf(acc1, 0.f);
        }
    }
    __syncthreads();
    {
        int nn = tid >> 4;       // node 0..31
        int cp = tid & 15;       // col pair: cols 2cp, 2cp+1
        int v2 = base + nn;
        if (v2 < N) {
            float a0 = 0.f, a1 = 0.f;
#pragma unroll
            for (int k = 0; k < F1; ++k) {
                float hv = sh[nn][k];
                a0 += hv * sW2[k * F2 + 2 * cp];
                a1 += hv * sW2[k * F2 + 2 * cp + 1];
            }
            float dv = dinv[v2];
            y2h[(size_t)v2 * 16 + cp] = __floats2half2_rn(a0 * dv, a1 * dv);
        }
    }
}

// ---------- layer2 aggregate fp16 (4 slots/node): out2 = dinv*(y2[self]+sum y2[src]) + b2 ----------
// 512 thr = 16 nodes x (4 slots x 8 lanes); lane reads 8B (4 fp16 cols)
__global__ void __launch_bounds__(512)
k_agg2(const uint2* __restrict__ y2h, const int* __restrict__ rowstart,
       const float* __restrict__ dinv, const int* __restrict__ csr,
       const float* __restrict__ b2, float4* __restrict__ out2, int N) {
    int tid = threadIdx.x;
    int ln = tid >> 5;           // local node 0..15
    int slot = (tid >> 3) & 3;   // edge slot 0..3
    int l = tid & 7;             // lane: cols 4l..4l+3
    int v = blockIdx.x * 16 + ln;
    if (v >= N) return;
    int st = rowstart[v];
    int en = rowstart[v + 1];
    float4 acc = make_float4(0.f, 0.f, 0.f, 0.f);
    for (int e = st + slot; e < en; e += 4) {
        int s = csr[e];
        uint2 u = y2h[(size_t)s * 8 + l];
        float2 f0 = __half22float2(*reinterpret_cast<__half2*>(&u.x));
        float2 f1 = __half22float2(*reinterpret_cast<__half2*>(&u.y));
        acc.x += f0.x; acc.y += f0.y; acc.z += f1.x; acc.w += f1.y;
    }
    acc.x += __shfl_xor(acc.x, 8);  acc.y += __shfl_xor(acc.y, 8);
    acc.z += __shfl_xor(acc.z, 8);  acc.w += __shfl_xor(acc.w, 8);
    acc.x += __shfl_xor(acc.x, 16); acc.y += __shfl_xor(acc.y, 16);
    acc.z += __shfl_xor(acc.z, 16); acc.w += __shfl_xor(acc.w, 16);
    if (slot == 0) {
        uint2 u = y2h[(size_t)v * 8 + l];
        float2 f0 = __half22float2(*reinterpret_cast<__half2*>(&u.x));
        float2 f1 = __half22float2(*reinterpret_cast<__half2*>(&u.y));
        float dv = dinv[v];
        float4 bb = ((const float4*)b2)[l];
        float4 o;
        o.x = (f0.x + acc.x) * dv + bb.x;
        o.y = (f0.y + acc.y) * dv + bb.y;
        o.z = (f1.x + acc.z) * dv + bb.z;
        o.w = (f1.y + acc.w) * dv + bb.w;
        out2[(size_t)v * 8 + l] = o;
    }
}

// ---------- fused mean-pool + MLP (graph bounds via binary search) ----------
__global__ void k_poolmlp(const float* __restrict__ out2, const int* __restrict__ batch,
                          const float* __restrict__ fc1w, const float* __restrict__ fc1b,
                          const float* __restrict__ fc2w, const float* __restrict__ fc2b,
                          float* __restrict__ out, int N, int G) {
    __shared__ float sW1[F2 * F2];
    __shared__ float sW2[F2 * F2];
    __shared__ float part[8][F2];
    __shared__ float gvec[F2];
    __shared__ float h1[F2];
    __shared__ int bounds[2];
    int tid = threadIdx.x;
    for (int i = tid; i < F2 * F2; i += 256) {
        sW1[i] = fc1w[i];
        sW2[i] = fc2w[i];
    }
    int g = blockIdx.x;
    if (tid < 2) {
        int target = g + tid;
        int lo = 0, hi = N;
        while (lo < hi) {
            int mid = (lo + hi) >> 1;
            if (batch[mid] < target) lo = mid + 1; else hi = mid;
        }
        bounds[tid] = lo;
    }
    __syncthreads();
    int st = bounds[0], en = bounds[1];
    int r = tid >> 5, c = tid & 31;
    float acc = 0.f;
    for (int v = st + r; v < en; v += 8) acc += out2[(size_t)v * F2 + c];
    part[r][c] = acc;
    __syncthreads();
    if (tid < F2) {
        float s = 0.f;
#pragma unroll
        for (int i = 0; i < 8; ++i) s += part[i][tid];
        float cnt = (float)(en - st);
        gvec[tid] = s / fmaxf(cnt, 1.0f);
    }
    __syncthreads();
    if (tid < F2) {
        float a = fc1b[tid];
#pragma unroll
        for (int k = 0; k < F2; ++k) a += gvec[k] * sW1[k * F2 + tid];
        h1[tid] = fmaxf(a, 0.f);
    }
    __syncthreads();
    if (tid < F2) {
        float a = fc2b[tid];
#pragma unroll
        for (int k = 0; k < F2; ++k) a += h1[k] * sW2[k * F2 + tid];
        out[(size_t)g * F2 + tid] = a;
    }
}

extern "C" void kernel_launch(void* const* d_in, const int* in_sizes, int n_in,
                              void* d_out, int out_size, void* d_ws, size_t ws_size,
                              hipStream_t stream) {
    const float* x    = (const float*)d_in[0];
    const int*   ei   = (const int*)d_in[1];
    const int*   batch= (const int*)d_in[2];
    const float* W1   = (const float*)d_in[3];
    const float* b1   = (const float*)d_in[4];
    const float* W2   = (const float*)d_in[5];
    const float* b2   = (const float*)d_in[6];
    const float* fc1w = (const float*)d_in[7];
    const float* fc1b = (const float*)d_in[8];
    const float* fc2w = (const float*)d_in[9];
    const float* fc2b = (const float*)d_in[10];
    float* out = (float*)d_out;

    const int N = in_sizes[0] / FIN;       // 100000
    const int E = in_sizes[1] / 2;         // 1250000
    const int G = out_size / F2;           // 512
    const int* src = ei;
    const int* dst = ei + E;
    const int NBK = (N + BNODES - 1) >> BSH;   // 196

    // ---- workspace layout (4-byte units) ----
    int* wsi = (int*)d_ws;
    int* bhist    = wsi;                   // NBK
    int* bbase    = bhist + NBK;           // NBK+1
    int* gcur     = bbase + NBK + 1;       // NBK
    int* rowstart = gcur + NBK;            // N+1
    int* csr      = rowstart + (N + 1);    // E
    unsigned* pairs = (unsigned*)(csr + E);// E (packed)
    size_t off = (size_t)(3 * NBK + 1 + N + 1) + 2 * (size_t)E;
    off = (off + 3) & ~(size_t)3;          // 16B align
    float* dinv = (float*)(wsi + off);               // N
    size_t nal = (size_t)((N + 3) & ~3);
    __half2* xnh = (__half2*)(dinv + nal);           // N*8 words (16 fp16/node)
    __half2* y2h = (__half2*)((int*)xnh + (size_t)N * 8);   // N*16 words (32 fp16/node)
    float* out2 = (float*)((int*)y2h + (size_t)N * 16);     // N*32

    const int B = 256;
    hipMemsetAsync(bhist, 0, (size_t)NBK * sizeof(int), stream);

    hipLaunchKernelGGL(k_bhist, dim3(256), dim3(B), 0, stream, dst, bhist, E, NBK);
    hipLaunchKernelGGL(k_bscan, dim3(1), dim3(B), 0, stream,
                       bhist, bbase, gcur, rowstart, NBK, N, E);
    hipLaunchKernelGGL(k_bscatter, dim3((E + TILE - 1) / TILE), dim3(SCT), 0, stream,
                       src, dst, gcur, pairs, E, NBK);
    hipLaunchKernelGGL(k_bsort, dim3(NBK), dim3(1024), 0, stream,
                       pairs, bbase, rowstart, dinv, csr, N);
    hipLaunchKernelGGL(k_xn, dim3(((long)N * 8 + B - 1) / B), dim3(B), 0, stream,
                       x, dinv, xnh, N);
    hipLaunchKernelGGL(k_agg1t, dim3((N + 31) / 32), dim3(512), 0, stream,
                       (const uint2*)xnh, rowstart, dinv, csr, W1, b1, W2, y2h, N);
    hipLaunchKernelGGL(k_agg2, dim3((N + 15) / 16), dim3(512), 0, stream,
                       (const uint2*)y2h, rowstart, dinv, csr, b2, (float4*)out2, N);
    hipLaunchKernelGGL(k_poolmlp, dim3(G), dim3(B), 0, stream,
                       out2, batch, fc1w, fc1b, fc2w, fc2b, out, N, G);
}